// Round 14
// baseline (13420.677 us; speedup 1.0000x reference)
//
#include <hip/hip_runtime.h>
#include <stdint.h>

#define T_SEQ   2048
#define NHEADS  16
#define HDIM    64
#define DMODEL  1024

typedef __attribute__((ext_vector_type(8))) _Float16 half8_t;
typedef __attribute__((ext_vector_type(4))) float    float4_t;

__device__ __forceinline__ unsigned short f2h(float f) {
  _Float16 h = (_Float16)f;
  return __builtin_bit_cast(unsigned short, h);
}
__device__ __forceinline__ float h2f(unsigned short u) {
  return (float)__builtin_bit_cast(_Float16, u);
}

// ================================================================ convert f32 -> f16 (verified r8)
__global__ __launch_bounds__(256) void cvt_f32_f16(const float* __restrict__ s,
                                                   unsigned short* __restrict__ d, int n4) {
  int i = blockIdx.x * 256 + threadIdx.x;
  if (i >= n4) return;
  float4 v = ((const float4*)s)[i];
  ushort4 o;
  o.x = f2h(v.x); o.y = f2h(v.y); o.z = f2h(v.z); o.w = f2h(v.w);
  ((ushort4*)d)[i] = o;
}

// ================================================================ MFMA f16 GEMM-NT (verified r8)
__global__ __launch_bounds__(256) void gemm_nt_f16(const unsigned short* __restrict__ A,
                                                   const unsigned short* __restrict__ B,
                                                   float* __restrict__ C) {
  __shared__ alignas(16) unsigned short As[128 * 32];
  __shared__ alignas(16) unsigned short Bs[128 * 32];
  const int tid  = threadIdx.x;
  const int lane = tid & 63, w = tid >> 6;
  const int c = lane & 15, g = lane >> 4;
  const int wr = w >> 1, wc = w & 1;
  const int m0 = blockIdx.y * 128, n0 = blockIdx.x * 128;

  float4_t acc[4][4];
#pragma unroll
  for (int m = 0; m < 4; ++m)
#pragma unroll
    for (int n = 0; n < 4; ++n) acc[m][n] = (float4_t){0.f, 0.f, 0.f, 0.f};

  for (int k0 = 0; k0 < 1024; k0 += 32) {
    half8_t av[2], bv2[2];
#pragma unroll
    for (int r = 0; r < 2; ++r) {
      const int ci = r * 256 + tid;
      const int row = ci >> 2, kc = (ci & 3) * 8;
      av[r]  = *(const half8_t*)&A[(size_t)(m0 + row) * 1024 + k0 + kc];
      bv2[r] = *(const half8_t*)&B[(size_t)(n0 + row) * 1024 + k0 + kc];
    }
    __syncthreads();
#pragma unroll
    for (int r = 0; r < 2; ++r) {
      const int ci = r * 256 + tid;
      const int row = ci >> 2, kc = (ci & 3) * 8;
      *(half8_t*)&As[row * 32 + kc] = av[r];
      *(half8_t*)&Bs[row * 32 + kc] = bv2[r];
    }
    __syncthreads();
    half8_t af[4], bf[4];
#pragma unroll
    for (int m = 0; m < 4; ++m) af[m] = *(const half8_t*)&As[(wr * 64 + m * 16 + c) * 32 + g * 8];
#pragma unroll
    for (int n = 0; n < 4; ++n) bf[n] = *(const half8_t*)&Bs[(wc * 64 + n * 16 + c) * 32 + g * 8];
#pragma unroll
    for (int m = 0; m < 4; ++m)
#pragma unroll
      for (int n = 0; n < 4; ++n)
        acc[m][n] = __builtin_amdgcn_mfma_f32_16x16x32_f16(af[m], bf[n], acc[m][n], 0, 0, 0);
  }
#pragma unroll
  for (int m = 0; m < 4; ++m)
#pragma unroll
    for (int j = 0; j < 4; ++j) {
      const int row = m0 + wr * 64 + m * 16 + g * 4 + j;
#pragma unroll
      for (int n = 0; n < 4; ++n) {
        const int col = n0 + wc * 64 + n * 16 + c;
        C[(size_t)row * 1024 + col] = acc[m][n][j];
      }
    }
}

// ================================================================ evolve + LayerNorm (verified)
__global__ __launch_bounds__(64) void evolve_ln_f32(
    const float* __restrict__ q, float* k,
    const float* __restrict__ er_p, const float* __restrict__ md_p,
    const float* __restrict__ tw, const float* __restrict__ qgamma,
    const float* __restrict__ qbeta, const float* __restrict__ kgamma,
    const float* __restrict__ kbeta, float* __restrict__ eq) {
  const int lane = threadIdx.x;
  const int t0 = blockIdx.x * 128;
  const int bh = blockIdx.y;
  const int b = bh >> 4, h = bh & 15;
  const float sig_er = 1.f / (1.f + expf(-er_p[0]));
  const float smd    = 1.f / (1.f + expf(-md_p[0]));
  const float wv = tw[lane];
  const float gq = qgamma[lane], bq = qbeta[lane];
  const float gk = kgamma[lane], bk = kbeta[lane];
  const size_t base = ((size_t)b * T_SEQ) * DMODEL + h * HDIM + lane;

  float mem = 0.f;
  const int start = (t0 >= 128) ? (t0 - 128) : 0;
  for (int t = start; t < t0; ++t)
    mem = 0.7f * mem + 0.3f * q[base + (size_t)t * DMODEL];

  for (int t = t0; t < t0 + 128; ++t) {
    const float qv = q[base + (size_t)t * DMODEL];
    const float kv = k[base + (size_t)t * DMODEL];
    const float ts = sinf(sig_er * (float)(t + 1) * wv);
    const float xq = qv + ts + smd * mem;
    const float xk = kv + 0.5f * ts + 0.3f * smd * mem;
    float s1 = xq, s2 = xq * xq, s3 = xk, s4 = xk * xk;
#pragma unroll
    for (int off = 32; off > 0; off >>= 1) {
      s1 += __shfl_xor(s1, off);
      s2 += __shfl_xor(s2, off);
      s3 += __shfl_xor(s3, off);
      s4 += __shfl_xor(s4, off);
    }
    const float mq = s1 * (1.f / 64.f);
    const float vq = fmaxf(s2 * (1.f / 64.f) - mq * mq, 0.f);
    const float mk = s3 * (1.f / 64.f);
    const float vk = fmaxf(s4 * (1.f / 64.f) - mk * mk, 0.f);
    eq[base + (size_t)t * DMODEL] = (xq - mq) * rsqrtf(vq + 1e-5f) * gq + bq;
    k [base + (size_t)t * DMODEL] = (xk - mk) * rsqrtf(vk + 1e-5f) * gk + bk;
    mem = 0.7f * mem + 0.3f * qv;
  }
}

// ================================================================ Probe A: r13 scaffold, NO Vt staging
// Identical to r13's attn_tiled_naive except the V^T LDS staging block is deleted;
// V is read scalar from global (verified r12 pattern). Barriers/loop kept verbatim.
__global__ __launch_bounds__(256) void attn_tiled_noVt(
    const unsigned short* __restrict__ eq, const unsigned short* __restrict__ ek,
    const unsigned short* __restrict__ v, float* __restrict__ out) {
  const int tid = threadIdx.x;
  const int lane = tid & 63, w = tid >> 6;
  const int qblk = blockIdx.x, bh = blockIdx.y;
  const int b = bh >> 4, h = bh & 15;
  const int qw = qblk * 64 + w * 16;
  const size_t head = ((size_t)b * T_SEQ) * DMODEL + h * HDIM;

  float qd[16], m[16], l[16], oo[16];
#pragma unroll
  for (int i = 0; i < 16; ++i) {
    qd[i] = h2f(eq[head + (size_t)(qw + i) * DMODEL + lane]);
    m[i] = -3.4e38f; l[i] = 0.f; oo[i] = 0.f;
  }

  const int ntiles = qblk * 2 + 2;
  for (int tile = 0; tile < ntiles; ++tile) {
    const int s0 = tile * 32;
    __syncthreads();                                  // B1 (skeleton preserved)
    __syncthreads();                                  // B2

    for (int sl = 0; sl < 32; ++sl) {
      const int s = s0 + sl;
      const float kd = h2f(ek[head + (size_t)s * DMODEL + lane]);
      const float vd = h2f(v [head + (size_t)s * DMODEL + lane]);  // direct global
#pragma unroll
      for (int i = 0; i < 16; ++i) {
        if (s > qw + i) continue;                     // wave-uniform
        float prod = qd[i] * kd;
#pragma unroll
        for (int off = 32; off > 0; off >>= 1) prod += __shfl_xor(prod, off);
        const float sc = prod * 0.125f;
        const float mn = fmaxf(m[i], sc);
        const float fac = __expf(m[i] - mn);
        const float wgt = __expf(sc - mn);
        l[i] = l[i] * fac + wgt;
        oo[i] = oo[i] * fac + wgt * vd;
        m[i] = mn;
      }
    }
  }

#pragma unroll
  for (int i = 0; i < 16; ++i)
    out[head + (size_t)(qw + i) * DMODEL + lane] = oo[i] / l[i];
}

// ================================================================ launch (identical to r13 except attn kernel)
extern "C" void kernel_launch(void* const* d_in, const int* in_sizes, int n_in,
                              void* d_out, int out_size, void* d_ws, size_t ws_size,
                              hipStream_t stream) {
  const float* x  = (const float*)d_in[0];
  const float* Wq = (const float*)d_in[1];
  const float* Wk = (const float*)d_in[2];
  const float* Wv = (const float*)d_in[3];
  const float* Wo = (const float*)d_in[4];
  const float* er = (const float*)d_in[5];
  const float* md = (const float*)d_in[6];
  const float* tw = (const float*)d_in[7];
  const float* qg = (const float*)d_in[8];
  const float* qb = (const float*)d_in[9];
  const float* kg = (const float*)d_in[10];
  const float* kb = (const float*)d_in[11];

  const size_t NX = (size_t)2 * T_SEQ * DMODEL;   // 4194304
  const size_t NW = (size_t)DMODEL * DMODEL;      // 1048576

  float* qf  = (float*)d_ws;      // [0,16) MB
  float* kf  = qf + NX;           // [16,32)
  float* vf  = kf + NX;           // [32,48)
  float* eqf = vf + NX;           // [48,64)

  unsigned short* xh  = (unsigned short*)eqf;     // [48,56)
  unsigned short* wqh = xh + NX;                  // [56,58)
  unsigned short* wkh = wqh + NW;                 // [58,60)
  unsigned short* wvh = wkh + NW;                 // [60,62)
  unsigned short* eqh = (unsigned short*)qf;      // [0,8)
  unsigned short* ekh = eqh + NX;                 // [8,16)
  unsigned short* vh  = (unsigned short*)eqf;     // [48,56)
  unsigned short* aoh = vh + NX;                  // [56,64)
  unsigned short* woh = (unsigned short*)qf;      // [0,2)

  const int n4x = (int)(NX / 4), n4w = (int)(NW / 4);

  cvt_f32_f16<<<n4x / 256, 256, 0, stream>>>(x,  xh,  n4x);
  cvt_f32_f16<<<n4w / 256, 256, 0, stream>>>(Wq, wqh, n4w);
  cvt_f32_f16<<<n4w / 256, 256, 0, stream>>>(Wk, wkh, n4w);
  cvt_f32_f16<<<n4w / 256, 256, 0, stream>>>(Wv, wvh, n4w);

  dim3 ggrid(DMODEL / 128, (2 * T_SEQ) / 128);   // (8, 32)
  gemm_nt_f16<<<ggrid, 256, 0, stream>>>(xh, wqh, qf);
  gemm_nt_f16<<<ggrid, 256, 0, stream>>>(xh, wkh, kf);
  gemm_nt_f16<<<ggrid, 256, 0, stream>>>(xh, wvh, vf);

  evolve_ln_f32<<<dim3(T_SEQ / 128, 32), 64, 0, stream>>>(qf, kf, er, md, tw,
                                                          qg, qb, kg, kb, eqf);

  cvt_f32_f16<<<n4x / 256, 256, 0, stream>>>(eqf, eqh, n4x);
  cvt_f32_f16<<<n4x / 256, 256, 0, stream>>>(kf,  ekh, n4x);
  cvt_f32_f16<<<n4x / 256, 256, 0, stream>>>(vf,  vh,  n4x);

  attn_tiled_noVt<<<dim3(T_SEQ / 64, 32), 256, 0, stream>>>(eqh, ekh, vh, vf);

  cvt_f32_f16<<<n4x / 256, 256, 0, stream>>>(vf, aoh, n4x);
  cvt_f32_f16<<<n4w / 256, 256, 0, stream>>>(Wo, woh, n4w);

  gemm_nt_f16<<<ggrid, 256, 0, stream>>>(aoh, woh, (float*)d_out);
}

// Round 15
// 418.163 us; speedup vs baseline: 32.0944x; 32.0944x over previous
//
#include <hip/hip_runtime.h>
#include <stdint.h>

#define T_SEQ   2048
#define NHEADS  16
#define HDIM    64
#define DMODEL  1024

typedef __attribute__((ext_vector_type(8))) _Float16 half8_t;
typedef __attribute__((ext_vector_type(4))) float    float4_t;

__device__ __forceinline__ unsigned short f2h(float f) {
  _Float16 h = (_Float16)f;
  return __builtin_bit_cast(unsigned short, h);
}
__device__ __forceinline__ float h2f(unsigned short u) {
  return (float)__builtin_bit_cast(_Float16, u);
}
__device__ __forceinline__ unsigned packh2(float a, float b) {
  return (unsigned)f2h(a) | ((unsigned)f2h(b) << 16);
}

// ================================================================ convert f32 -> f16 (verified r8)
__global__ __launch_bounds__(256) void cvt_f32_f16(const float* __restrict__ s,
                                                   unsigned short* __restrict__ d, int n4) {
  int i = blockIdx.x * 256 + threadIdx.x;
  if (i >= n4) return;
  float4 v = ((const float4*)s)[i];
  ushort4 o;
  o.x = f2h(v.x); o.y = f2h(v.y); o.z = f2h(v.z); o.w = f2h(v.w);
  ((ushort4*)d)[i] = o;
}

// ================================================================ MFMA f16 GEMM-NT (verified r8)
__global__ __launch_bounds__(256) void gemm_nt_f16(const unsigned short* __restrict__ A,
                                                   const unsigned short* __restrict__ B,
                                                   float* __restrict__ C) {
  __shared__ alignas(16) unsigned short As[128 * 32];
  __shared__ alignas(16) unsigned short Bs[128 * 32];
  const int tid  = threadIdx.x;
  const int lane = tid & 63, w = tid >> 6;
  const int c = lane & 15, g = lane >> 4;
  const int wr = w >> 1, wc = w & 1;
  const int m0 = blockIdx.y * 128, n0 = blockIdx.x * 128;

  float4_t acc[4][4];
#pragma unroll
  for (int m = 0; m < 4; ++m)
#pragma unroll
    for (int n = 0; n < 4; ++n) acc[m][n] = (float4_t){0.f, 0.f, 0.f, 0.f};

  for (int k0 = 0; k0 < 1024; k0 += 32) {
    half8_t av[2], bv2[2];
#pragma unroll
    for (int r = 0; r < 2; ++r) {
      const int ci = r * 256 + tid;
      const int row = ci >> 2, kc = (ci & 3) * 8;
      av[r]  = *(const half8_t*)&A[(size_t)(m0 + row) * 1024 + k0 + kc];
      bv2[r] = *(const half8_t*)&B[(size_t)(n0 + row) * 1024 + k0 + kc];
    }
    __syncthreads();
#pragma unroll
    for (int r = 0; r < 2; ++r) {
      const int ci = r * 256 + tid;
      const int row = ci >> 2, kc = (ci & 3) * 8;
      *(half8_t*)&As[row * 32 + kc] = av[r];
      *(half8_t*)&Bs[row * 32 + kc] = bv2[r];
    }
    __syncthreads();
    half8_t af[4], bf[4];
#pragma unroll
    for (int m = 0; m < 4; ++m) af[m] = *(const half8_t*)&As[(wr * 64 + m * 16 + c) * 32 + g * 8];
#pragma unroll
    for (int n = 0; n < 4; ++n) bf[n] = *(const half8_t*)&Bs[(wc * 64 + n * 16 + c) * 32 + g * 8];
#pragma unroll
    for (int m = 0; m < 4; ++m)
#pragma unroll
      for (int n = 0; n < 4; ++n)
        acc[m][n] = __builtin_amdgcn_mfma_f32_16x16x32_f16(af[m], bf[n], acc[m][n], 0, 0, 0);
  }
#pragma unroll
  for (int m = 0; m < 4; ++m)
#pragma unroll
    for (int j = 0; j < 4; ++j) {
      const int row = m0 + wr * 64 + m * 16 + g * 4 + j;
#pragma unroll
      for (int n = 0; n < 4; ++n) {
        const int col = n0 + wc * 64 + n * 16 + c;
        C[(size_t)row * 1024 + col] = acc[m][n][j];
      }
    }
}

// ================================================================ evolve + LayerNorm (verified)
__global__ __launch_bounds__(64) void evolve_ln_f32(
    const float* __restrict__ q, float* k,
    const float* __restrict__ er_p, const float* __restrict__ md_p,
    const float* __restrict__ tw, const float* __restrict__ qgamma,
    const float* __restrict__ qbeta, const float* __restrict__ kgamma,
    const float* __restrict__ kbeta, float* __restrict__ eq) {
  const int lane = threadIdx.x;
  const int t0 = blockIdx.x * 128;
  const int bh = blockIdx.y;
  const int b = bh >> 4, h = bh & 15;
  const float sig_er = 1.f / (1.f + expf(-er_p[0]));
  const float smd    = 1.f / (1.f + expf(-md_p[0]));
  const float wv = tw[lane];
  const float gq = qgamma[lane], bq = qbeta[lane];
  const float gk = kgamma[lane], bk = kbeta[lane];
  const size_t base = ((size_t)b * T_SEQ) * DMODEL + h * HDIM + lane;

  float mem = 0.f;
  const int start = (t0 >= 128) ? (t0 - 128) : 0;
  for (int t = start; t < t0; ++t)
    mem = 0.7f * mem + 0.3f * q[base + (size_t)t * DMODEL];

  for (int t = t0; t < t0 + 128; ++t) {
    const float qv = q[base + (size_t)t * DMODEL];
    const float kv = k[base + (size_t)t * DMODEL];
    const float ts = sinf(sig_er * (float)(t + 1) * wv);
    const float xq = qv + ts + smd * mem;
    const float xk = kv + 0.5f * ts + 0.3f * smd * mem;
    float s1 = xq, s2 = xq * xq, s3 = xk, s4 = xk * xk;
#pragma unroll
    for (int off = 32; off > 0; off >>= 1) {
      s1 += __shfl_xor(s1, off);
      s2 += __shfl_xor(s2, off);
      s3 += __shfl_xor(s3, off);
      s4 += __shfl_xor(s4, off);
    }
    const float mq = s1 * (1.f / 64.f);
    const float vq = fmaxf(s2 * (1.f / 64.f) - mq * mq, 0.f);
    const float mk = s3 * (1.f / 64.f);
    const float vk = fmaxf(s4 * (1.f / 64.f) - mk * mk, 0.f);
    eq[base + (size_t)t * DMODEL] = (xq - mq) * rsqrtf(vq + 1e-5f) * gq + bq;
    k [base + (size_t)t * DMODEL] = (xk - mk) * rsqrtf(vk + 1e-5f) * gk + bk;
    mem = 0.7f * mem + 0.3f * qv;
  }
}

// ================================================================ MFMA flash attention, fixed staging
// r9's structure with the two _Float16 vector-element touches removed:
// (1) Vt staging via uint4 + integer shifts; (2) pa built via f2h packing + bit_cast.
__global__ __launch_bounds__(256) void attn_mfma(
    const unsigned short* __restrict__ eq, const unsigned short* __restrict__ ek,
    const unsigned short* __restrict__ v, float* __restrict__ o) {
  __shared__ alignas(16) unsigned short Vt[64][40];   // V^T tile [d][s]
  __shared__ alignas(16) float Ssh[4][16][36];        // per-wave S [q][s] (+pad)
  __shared__ float Alds[4][16];
  __shared__ float Llds[4][16];
  const int tid = threadIdx.x;
  const int lane = tid & 63, w = tid >> 6;
  const int c = lane & 15, g = lane >> 4;
  const int qblk = blockIdx.x, bh = blockIdx.y;
  const int b = bh >> 4, h = bh & 15;
  const int qw = qblk * 64 + w * 16;
  const int qrow = qw + c;
  const size_t head = ((size_t)b * T_SEQ) * DMODEL + h * HDIM;

  const half8_t aq0 = *(const half8_t*)(eq + head + (size_t)qrow * DMODEL + g * 8);
  const half8_t aq1 = *(const half8_t*)(eq + head + (size_t)qrow * DMODEL + 32 + g * 8);

  float4_t acc[4];
#pragma unroll
  for (int n = 0; n < 4; ++n) acc[n] = (float4_t){0.f, 0.f, 0.f, 0.f};
  float mrun = -1e30f, lsum = 0.f;

  const int ntiles = qblk * 2 + 2;
  for (int tile = 0; tile < ntiles; ++tile) {
    const int s0 = tile * 32;
    __syncthreads();                                  // B1
    {  // V tile -> Vt, uint unpack (NO _Float16 element extraction)
      const int srow = tid >> 3, dc = tid & 7;
      const uint4 vv = *(const uint4*)(v + head + (size_t)(s0 + srow) * DMODEL + dc * 8);
      Vt[dc * 8 + 0][srow] = (unsigned short)(vv.x & 0xffffu);
      Vt[dc * 8 + 1][srow] = (unsigned short)(vv.x >> 16);
      Vt[dc * 8 + 2][srow] = (unsigned short)(vv.y & 0xffffu);
      Vt[dc * 8 + 3][srow] = (unsigned short)(vv.y >> 16);
      Vt[dc * 8 + 4][srow] = (unsigned short)(vv.z & 0xffffu);
      Vt[dc * 8 + 5][srow] = (unsigned short)(vv.z >> 16);
      Vt[dc * 8 + 6][srow] = (unsigned short)(vv.w & 0xffffu);
      Vt[dc * 8 + 7][srow] = (unsigned short)(vv.w >> 16);
    }
#pragma unroll
    for (int sub = 0; sub < 2; ++sub) {
      const unsigned short* ekr = ek + head + (size_t)(s0 + sub * 16 + c) * DMODEL;
      const half8_t bk0 = *(const half8_t*)(ekr + g * 8);
      const half8_t bk1 = *(const half8_t*)(ekr + 32 + g * 8);
      float4_t z = (float4_t){0.f, 0.f, 0.f, 0.f};
      z = __builtin_amdgcn_mfma_f32_16x16x32_f16(aq0, bk0, z, 0, 0, 0);
      z = __builtin_amdgcn_mfma_f32_16x16x32_f16(aq1, bk1, z, 0, 0, 0);
#pragma unroll
      for (int j = 0; j < 4; ++j)
        Ssh[w][g * 4 + j][sub * 16 + c] = z[j] * 0.125f;   // float extraction (verified)
    }
    __syncthreads();                                  // B2: Ssh + Vt visible

    float p[8];
    float tmax = -1e30f;
#pragma unroll
    for (int e = 0; e < 8; ++e) {
      const int sa = s0 + g * 8 + e;
      const float val = (sa <= qrow) ? Ssh[w][c][g * 8 + e] : -1e30f;
      p[e] = val;
      tmax = fmaxf(tmax, val);
    }
    tmax = fmaxf(tmax, __shfl_xor(tmax, 16));
    tmax = fmaxf(tmax, __shfl_xor(tmax, 32));
    const float mnew = fmaxf(mrun, tmax);
    const float alpha = __expf(mrun - mnew);
    mrun = mnew;
    float psum = 0.f;
#pragma unroll
    for (int e = 0; e < 8; ++e) {
      p[e] = __expf(p[e] - mnew);
      psum += p[e];
    }
    psum += __shfl_xor(psum, 16);
    psum += __shfl_xor(psum, 32);
    lsum = lsum * alpha + psum;
    if (g == 0) Alds[w][c] = alpha;

    // pa: pack own P into A-frag via f2h + shifts (NO _Float16 element writes)
    uint4 pu;
    pu.x = packh2(p[0], p[1]);
    pu.y = packh2(p[2], p[3]);
    pu.z = packh2(p[4], p[5]);
    pu.w = packh2(p[6], p[7]);
    const half8_t pa = __builtin_bit_cast(half8_t, pu);
    __syncthreads();                                  // B3: Alds visible

    float af[4];
#pragma unroll
    for (int j = 0; j < 4; ++j) af[j] = Alds[w][g * 4 + j];
#pragma unroll
    for (int n = 0; n < 4; ++n) {
      acc[n][0] *= af[0]; acc[n][1] *= af[1];
      acc[n][2] *= af[2]; acc[n][3] *= af[3];
    }
#pragma unroll
    for (int n = 0; n < 4; ++n) {
      const half8_t bv = *(const half8_t*)&Vt[n * 16 + c][g * 8];  // whole-vector (verified)
      acc[n] = __builtin_amdgcn_mfma_f32_16x16x32_f16(pa, bv, acc[n], 0, 0, 0);
    }
  }

  if (g == 0) Llds[w][c] = lsum;
  __syncthreads();
  float lj[4];
#pragma unroll
  for (int j = 0; j < 4; ++j) lj[j] = 1.f / Llds[w][g * 4 + j];
#pragma unroll
  for (int n = 0; n < 4; ++n)
#pragma unroll
    for (int j = 0; j < 4; ++j)
      o[head + (size_t)(qw + g * 4 + j) * DMODEL + n * 16 + c] = acc[n][j] * lj[j];
}

// ================================================================ launch (identical to r9/r13)
extern "C" void kernel_launch(void* const* d_in, const int* in_sizes, int n_in,
                              void* d_out, int out_size, void* d_ws, size_t ws_size,
                              hipStream_t stream) {
  const float* x  = (const float*)d_in[0];
  const float* Wq = (const float*)d_in[1];
  const float* Wk = (const float*)d_in[2];
  const float* Wv = (const float*)d_in[3];
  const float* Wo = (const float*)d_in[4];
  const float* er = (const float*)d_in[5];
  const float* md = (const float*)d_in[6];
  const float* tw = (const float*)d_in[7];
  const float* qg = (const float*)d_in[8];
  const float* qb = (const float*)d_in[9];
  const float* kg = (const float*)d_in[10];
  const float* kb = (const float*)d_in[11];

  const size_t NX = (size_t)2 * T_SEQ * DMODEL;   // 4194304
  const size_t NW = (size_t)DMODEL * DMODEL;      // 1048576

  float* qf  = (float*)d_ws;      // [0,16) MB
  float* kf  = qf + NX;           // [16,32)
  float* vf  = kf + NX;           // [32,48)
  float* eqf = vf + NX;           // [48,64)

  unsigned short* xh  = (unsigned short*)eqf;     // [48,56)
  unsigned short* wqh = xh + NX;                  // [56,58)
  unsigned short* wkh = wqh + NW;                 // [58,60)
  unsigned short* wvh = wkh + NW;                 // [60,62)
  unsigned short* eqh = (unsigned short*)qf;      // [0,8)
  unsigned short* ekh = eqh + NX;                 // [8,16)
  unsigned short* vh  = (unsigned short*)eqf;     // [48,56)
  unsigned short* aoh = vh + NX;                  // [56,64)
  unsigned short* woh = (unsigned short*)qf;      // [0,2)

  const int n4x = (int)(NX / 4), n4w = (int)(NW / 4);

  cvt_f32_f16<<<n4x / 256, 256, 0, stream>>>(x,  xh,  n4x);
  cvt_f32_f16<<<n4w / 256, 256, 0, stream>>>(Wq, wqh, n4w);
  cvt_f32_f16<<<n4w / 256, 256, 0, stream>>>(Wk, wkh, n4w);
  cvt_f32_f16<<<n4w / 256, 256, 0, stream>>>(Wv, wvh, n4w);

  dim3 ggrid(DMODEL / 128, (2 * T_SEQ) / 128);   // (8, 32)
  gemm_nt_f16<<<ggrid, 256, 0, stream>>>(xh, wqh, qf);
  gemm_nt_f16<<<ggrid, 256, 0, stream>>>(xh, wkh, kf);
  gemm_nt_f16<<<ggrid, 256, 0, stream>>>(xh, wvh, vf);

  evolve_ln_f32<<<dim3(T_SEQ / 128, 32), 64, 0, stream>>>(qf, kf, er, md, tw,
                                                          qg, qb, kg, kb, eqf);

  cvt_f32_f16<<<n4x / 256, 256, 0, stream>>>(eqf, eqh, n4x);
  cvt_f32_f16<<<n4x / 256, 256, 0, stream>>>(kf,  ekh, n4x);
  cvt_f32_f16<<<n4x / 256, 256, 0, stream>>>(vf,  vh,  n4x);

  attn_mfma<<<dim3(T_SEQ / 64, 32), 256, 0, stream>>>(eqh, ekh, vh, vf);

  cvt_f32_f16<<<n4x / 256, 256, 0, stream>>>(vf, aoh, n4x);
  cvt_f32_f16<<<n4w / 256, 256, 0, stream>>>(Wo, woh, n4w);

  gemm_nt_f16<<<ggrid, 256, 0, stream>>>(aoh, woh, (float*)d_out);
}

// Round 16
// 317.092 us; speedup vs baseline: 42.3243x; 1.3187x over previous
//
#include <hip/hip_runtime.h>
#include <stdint.h>

#define T_SEQ   2048
#define NHEADS  16
#define HDIM    64
#define DMODEL  1024

typedef __attribute__((ext_vector_type(8))) _Float16 half8_t;
typedef __attribute__((ext_vector_type(4))) float    float4_t;

__device__ __forceinline__ unsigned short f2h(float f) {
  _Float16 h = (_Float16)f;
  return __builtin_bit_cast(unsigned short, h);
}
__device__ __forceinline__ unsigned packh2(float a, float b) {
  return (unsigned)f2h(a) | ((unsigned)f2h(b) << 16);
}
__device__ __forceinline__ unsigned packu2(unsigned short a, unsigned short b) {
  return (unsigned)a | ((unsigned)b << 16);
}

// ================================================================ convert f32 -> f16 (verified r8)
__global__ __launch_bounds__(256) void cvt_f32_f16(const float* __restrict__ s,
                                                   unsigned short* __restrict__ d, int n4) {
  int i = blockIdx.x * 256 + threadIdx.x;
  if (i >= n4) return;
  float4 v = ((const float4*)s)[i];
  ushort4 o;
  o.x = f2h(v.x); o.y = f2h(v.y); o.z = f2h(v.z); o.w = f2h(v.w);
  ((ushort4*)d)[i] = o;
}

// ================================================================ MFMA f16 GEMM-NT (verified r8)
__device__ __forceinline__ void storeC(float* p, float v) { *p = v; }
__device__ __forceinline__ void storeC(unsigned short* p, float v) { *p = f2h(v); }

template <typename OutT>
__global__ __launch_bounds__(256) void gemm_nt_f16(const unsigned short* __restrict__ A,
                                                   const unsigned short* __restrict__ B,
                                                   OutT* __restrict__ C) {
  __shared__ alignas(16) unsigned short As[128 * 32];
  __shared__ alignas(16) unsigned short Bs[128 * 32];
  const int tid  = threadIdx.x;
  const int lane = tid & 63, w = tid >> 6;
  const int c = lane & 15, g = lane >> 4;
  const int wr = w >> 1, wc = w & 1;
  const int m0 = blockIdx.y * 128, n0 = blockIdx.x * 128;

  float4_t acc[4][4];
#pragma unroll
  for (int m = 0; m < 4; ++m)
#pragma unroll
    for (int n = 0; n < 4; ++n) acc[m][n] = (float4_t){0.f, 0.f, 0.f, 0.f};

  for (int k0 = 0; k0 < 1024; k0 += 32) {
    half8_t av[2], bv2[2];
#pragma unroll
    for (int r = 0; r < 2; ++r) {
      const int ci = r * 256 + tid;
      const int row = ci >> 2, kc = (ci & 3) * 8;
      av[r]  = *(const half8_t*)&A[(size_t)(m0 + row) * 1024 + k0 + kc];
      bv2[r] = *(const half8_t*)&B[(size_t)(n0 + row) * 1024 + k0 + kc];
    }
    __syncthreads();
#pragma unroll
    for (int r = 0; r < 2; ++r) {
      const int ci = r * 256 + tid;
      const int row = ci >> 2, kc = (ci & 3) * 8;
      *(half8_t*)&As[row * 32 + kc] = av[r];
      *(half8_t*)&Bs[row * 32 + kc] = bv2[r];
    }
    __syncthreads();
    half8_t af[4], bf[4];
#pragma unroll
    for (int m = 0; m < 4; ++m) af[m] = *(const half8_t*)&As[(wr * 64 + m * 16 + c) * 32 + g * 8];
#pragma unroll
    for (int n = 0; n < 4; ++n) bf[n] = *(const half8_t*)&Bs[(wc * 64 + n * 16 + c) * 32 + g * 8];
#pragma unroll
    for (int m = 0; m < 4; ++m)
#pragma unroll
      for (int n = 0; n < 4; ++n)
        acc[m][n] = __builtin_amdgcn_mfma_f32_16x16x32_f16(af[m], bf[n], acc[m][n], 0, 0, 0);
  }
#pragma unroll
  for (int m = 0; m < 4; ++m)
#pragma unroll
    for (int j = 0; j < 4; ++j) {
      const int row = m0 + wr * 64 + m * 16 + g * 4 + j;
#pragma unroll
      for (int n = 0; n < 4; ++n) {
        const int col = n0 + wc * 64 + n * 16 + c;
        storeC(C + (size_t)row * 1024 + col, acc[m][n][j]);
      }
    }
}

// ================================================================ evolve + LayerNorm (verified math, f16 out)
__global__ __launch_bounds__(64) void evolve_ln_f32(
    const float* __restrict__ q, const float* __restrict__ k,
    const float* __restrict__ er_p, const float* __restrict__ md_p,
    const float* __restrict__ tw, const float* __restrict__ qgamma,
    const float* __restrict__ qbeta, const float* __restrict__ kgamma,
    const float* __restrict__ kbeta,
    unsigned short* __restrict__ eq, unsigned short* __restrict__ ek) {
  const int lane = threadIdx.x;
  const int t0 = blockIdx.x * 128;
  const int bh = blockIdx.y;
  const int b = bh >> 4, h = bh & 15;
  const float sig_er = 1.f / (1.f + expf(-er_p[0]));
  const float smd    = 1.f / (1.f + expf(-md_p[0]));
  const float wv = tw[lane];
  const float gq = qgamma[lane], bq = qbeta[lane];
  const float gk = kgamma[lane], bk = kbeta[lane];
  const size_t base = ((size_t)b * T_SEQ) * DMODEL + h * HDIM + lane;

  float mem = 0.f;
  const int start = (t0 >= 128) ? (t0 - 128) : 0;
  for (int t = start; t < t0; ++t)
    mem = 0.7f * mem + 0.3f * q[base + (size_t)t * DMODEL];

  for (int t = t0; t < t0 + 128; ++t) {
    const float qv = q[base + (size_t)t * DMODEL];
    const float kv = k[base + (size_t)t * DMODEL];
    const float ts = sinf(sig_er * (float)(t + 1) * wv);
    const float xq = qv + ts + smd * mem;
    const float xk = kv + 0.5f * ts + 0.3f * smd * mem;
    float s1 = xq, s2 = xq * xq, s3 = xk, s4 = xk * xk;
#pragma unroll
    for (int off = 32; off > 0; off >>= 1) {
      s1 += __shfl_xor(s1, off);
      s2 += __shfl_xor(s2, off);
      s3 += __shfl_xor(s3, off);
      s4 += __shfl_xor(s4, off);
    }
    const float mq = s1 * (1.f / 64.f);
    const float vq = fmaxf(s2 * (1.f / 64.f) - mq * mq, 0.f);
    const float mk = s3 * (1.f / 64.f);
    const float vk = fmaxf(s4 * (1.f / 64.f) - mk * mk, 0.f);
    eq[base + (size_t)t * DMODEL] = f2h((xq - mq) * rsqrtf(vq + 1e-5f) * gq + bq);
    ek[base + (size_t)t * DMODEL] = f2h((xk - mk) * rsqrtf(vk + 1e-5f) * gk + bk);
    mem = 0.7f * mem + 0.3f * qv;
  }
}

// ================================================================ MFMA flash attention, barrier-free + folded
// grid (16, B*H), block 256 = 4 independent waves. Wave w handles substrip pair
// (p, 127-p), p = blockIdx.x*4+w; each substrip = 16 q rows. Per-wave tiles =
// (qw>>5)+1 (exact causal). No __syncthreads: per-wave Ssh/Alds/Llds only; V
// B-frags loaded directly from global (L2-resident). f16 output.
__global__ __launch_bounds__(256) void attn_fused(
    const unsigned short* __restrict__ eq, const unsigned short* __restrict__ ek,
    const unsigned short* __restrict__ v, unsigned short* __restrict__ o) {
  __shared__ alignas(16) float Ssh[4][16][36];   // per-wave S [q][s] (+pad)
  __shared__ float Alds[4][16];
  __shared__ float Llds[4][16];
  const int tid = threadIdx.x;
  const int lane = tid & 63, w = tid >> 6;
  const int c = lane & 15, g = lane >> 4;
  const int p = blockIdx.x * 4 + w;              // 0..63
  const int bh = blockIdx.y;
  const int b = bh >> 4, h = bh & 15;
  const size_t head = ((size_t)b * T_SEQ) * DMODEL + h * HDIM;

  for (int half = 0; half < 2; ++half) {
    const int sub = half ? (127 - p) : p;        // substrip 0..127
    const int qw = sub * 16;
    const int qrow = qw + c;

    const half8_t aq0 = *(const half8_t*)(eq + head + (size_t)qrow * DMODEL + g * 8);
    const half8_t aq1 = *(const half8_t*)(eq + head + (size_t)qrow * DMODEL + 32 + g * 8);

    float4_t acc[4];
#pragma unroll
    for (int n = 0; n < 4; ++n) acc[n] = (float4_t){0.f, 0.f, 0.f, 0.f};
    float mrun = -1e30f, lsum = 0.f;

    const int ntiles = (qw >> 5) + 1;
    for (int tile = 0; tile < ntiles; ++tile) {
      const int s0 = tile * 32;
      // ---- QK^T (verified r15 pattern), S -> per-wave Ssh
#pragma unroll
      for (int st = 0; st < 2; ++st) {
        const unsigned short* ekr = ek + head + (size_t)(s0 + st * 16 + c) * DMODEL;
        const half8_t bk0 = *(const half8_t*)(ekr + g * 8);
        const half8_t bk1 = *(const half8_t*)(ekr + 32 + g * 8);
        float4_t z = (float4_t){0.f, 0.f, 0.f, 0.f};
        z = __builtin_amdgcn_mfma_f32_16x16x32_f16(aq0, bk0, z, 0, 0, 0);
        z = __builtin_amdgcn_mfma_f32_16x16x32_f16(aq1, bk1, z, 0, 0, 0);
#pragma unroll
        for (int j = 0; j < 4; ++j)
          Ssh[w][g * 4 + j][st * 16 + c] = z[j] * 0.125f;
      }
      // (same-wave LDS ordering via compiler lgkmcnt — no barrier)

      // ---- softmax on own q-row (slots g*8..g*8+7)
      float pf[8];
      float tmax = -1e30f;
#pragma unroll
      for (int e = 0; e < 8; ++e) {
        const int sa = s0 + g * 8 + e;
        const float val = (sa <= qrow) ? Ssh[w][c][g * 8 + e] : -1e30f;
        pf[e] = val;
        tmax = fmaxf(tmax, val);
      }
      tmax = fmaxf(tmax, __shfl_xor(tmax, 16));
      tmax = fmaxf(tmax, __shfl_xor(tmax, 32));
      const float mnew = fmaxf(mrun, tmax);
      const float alpha = __expf(mrun - mnew);
      mrun = mnew;
      float psum = 0.f;
#pragma unroll
      for (int e = 0; e < 8; ++e) {
        pf[e] = __expf(pf[e] - mnew);
        psum += pf[e];
      }
      psum += __shfl_xor(psum, 16);
      psum += __shfl_xor(psum, 32);
      lsum = lsum * alpha + psum;
      if (g == 0) Alds[w][c] = alpha;

      // pa: pack own P (verified r15 idiom)
      uint4 pu;
      pu.x = packh2(pf[0], pf[1]);
      pu.y = packh2(pf[2], pf[3]);
      pu.z = packh2(pf[4], pf[5]);
      pu.w = packh2(pf[6], pf[7]);
      const half8_t pa = __builtin_bit_cast(half8_t, pu);

      float af[4];
#pragma unroll
      for (int j = 0; j < 4; ++j) af[j] = Alds[w][g * 4 + j];
#pragma unroll
      for (int n = 0; n < 4; ++n) {
        acc[n][0] *= af[0]; acc[n][1] *= af[1];
        acc[n][2] *= af[2]; acc[n][3] *= af[3];
      }
      // ---- PV: B-frag V^T[d=n*16+c][s=g*8+e] direct from global (L2)
      const unsigned short* vp = v + head + (size_t)(s0 + g * 8) * DMODEL + c;
#pragma unroll
      for (int n = 0; n < 4; ++n) {
        const unsigned short* vq2 = vp + n * 16;
        uint4 bu;
        bu.x = packu2(vq2[0 * DMODEL], vq2[1 * DMODEL]);
        bu.y = packu2(vq2[2 * DMODEL], vq2[3 * DMODEL]);
        bu.z = packu2(vq2[4 * DMODEL], vq2[5 * DMODEL]);
        bu.w = packu2(vq2[6 * DMODEL], vq2[7 * DMODEL]);
        const half8_t bv = __builtin_bit_cast(half8_t, bu);
        acc[n] = __builtin_amdgcn_mfma_f32_16x16x32_f16(pa, bv, acc[n], 0, 0, 0);
      }
    }

    if (g == 0) Llds[w][c] = lsum;
    float lj[4];
#pragma unroll
    for (int j = 0; j < 4; ++j) lj[j] = 1.f / Llds[w][g * 4 + j];
#pragma unroll
    for (int n = 0; n < 4; ++n)
#pragma unroll
      for (int j = 0; j < 4; ++j)
        o[head + (size_t)(qw + g * 4 + j) * DMODEL + n * 16 + c] = f2h(acc[n][j] * lj[j]);
  }
}

// ================================================================ launch
extern "C" void kernel_launch(void* const* d_in, const int* in_sizes, int n_in,
                              void* d_out, int out_size, void* d_ws, size_t ws_size,
                              hipStream_t stream) {
  const float* x  = (const float*)d_in[0];
  const float* Wq = (const float*)d_in[1];
  const float* Wk = (const float*)d_in[2];
  const float* Wv = (const float*)d_in[3];
  const float* Wo = (const float*)d_in[4];
  const float* er = (const float*)d_in[5];
  const float* md = (const float*)d_in[6];
  const float* tw = (const float*)d_in[7];
  const float* qg = (const float*)d_in[8];
  const float* qb = (const float*)d_in[9];
  const float* kg = (const float*)d_in[10];
  const float* kb = (const float*)d_in[11];

  const size_t NX = (size_t)2 * T_SEQ * DMODEL;   // 4194304
  const size_t NW = (size_t)DMODEL * DMODEL;      // 1048576

  // Workspace 64 MB with dead-region overlay:
  // [0,8)   xh (f16 x)        -> eqh (evolve out; xh dead after QKV GEMMs)
  // [8,10)  woh   [10,16) wq/wk/wv h
  // [16,32) qf f32 (Q out)    -> dead after evolve
  // [32,48) kf f32 (K out)    -> [32,40) aoh (attn out; kf dead after evolve)
  // [48,56) ekh f16 (evolve out)
  // [56,64) vh f16 (V-GEMM direct out)
  unsigned short* xh  = (unsigned short*)d_ws;            // [0,8)
  unsigned short* woh = xh + NX;                          // [8,10)
  unsigned short* wqh = woh + NW;                         // [10,12)
  unsigned short* wkh = wqh + NW;                         // [12,14)
  unsigned short* wvh = wkh + NW;                         // [14,16)
  float* qf  = (float*)(wvh + NW);                        // [16,32)
  float* kf  = qf + NX;                                   // [32,48)
  unsigned short* ekh = (unsigned short*)(kf + NX);       // [48,56)
  unsigned short* vh  = ekh + NX;                         // [56,64)
  unsigned short* eqh = xh;                               // [0,8) overlay
  unsigned short* aoh = (unsigned short*)kf;              // [32,40) overlay

  const int n4x = (int)(NX / 4), n4w = (int)(NW / 4);

  cvt_f32_f16<<<n4x / 256, 256, 0, stream>>>(x,  xh,  n4x);
  cvt_f32_f16<<<n4w / 256, 256, 0, stream>>>(Wq, wqh, n4w);
  cvt_f32_f16<<<n4w / 256, 256, 0, stream>>>(Wk, wkh, n4w);
  cvt_f32_f16<<<n4w / 256, 256, 0, stream>>>(Wv, wvh, n4w);
  cvt_f32_f16<<<n4w / 256, 256, 0, stream>>>(Wo, woh, n4w);

  dim3 ggrid(DMODEL / 128, (2 * T_SEQ) / 128);   // (8, 32)
  gemm_nt_f16<float><<<ggrid, 256, 0, stream>>>(xh, wqh, qf);
  gemm_nt_f16<float><<<ggrid, 256, 0, stream>>>(xh, wkh, kf);
  gemm_nt_f16<unsigned short><<<ggrid, 256, 0, stream>>>(xh, wvh, vh);

  // evolve: reads qf/kf f32, writes eqh (over dead xh) + ekh f16
  evolve_ln_f32<<<dim3(T_SEQ / 128, 32), 64, 0, stream>>>(qf, kf, er, md, tw,
                                                          qg, qb, kg, kb, eqh, ekh);

  // attention: barrier-free, folded; writes f16 aoh (over dead kf)
  attn_fused<<<dim3(16, 32), 256, 0, stream>>>(eqh, ekh, vh, aoh);

  gemm_nt_f16<float><<<ggrid, 256, 0, stream>>>(aoh, woh, (float*)d_out);
}

// Round 17
// 252.346 us; speedup vs baseline: 53.1836x; 1.2566x over previous
//
#include <hip/hip_runtime.h>
#include <stdint.h>

#define T_SEQ   2048
#define NHEADS  16
#define HDIM    64
#define DMODEL  1024

typedef __attribute__((ext_vector_type(8))) _Float16 half8_t;
typedef __attribute__((ext_vector_type(4))) float    float4_t;

typedef __attribute__((address_space(1))) unsigned char ga_u8;
typedef __attribute__((address_space(3))) unsigned char lds_u8;

__device__ __forceinline__ unsigned short f2h(float f) {
  _Float16 h = (_Float16)f;
  return __builtin_bit_cast(unsigned short, h);
}
__device__ __forceinline__ unsigned packh2(float a, float b) {
  return (unsigned)f2h(a) | ((unsigned)f2h(b) << 16);
}
__device__ __forceinline__ unsigned packu2(unsigned short a, unsigned short b) {
  return (unsigned)a | ((unsigned)b << 16);
}
__device__ __forceinline__ void async_copy16(const void* g, void* l) {
  __builtin_amdgcn_global_load_lds((ga_u8*)g, (lds_u8*)l, 16, 0, 0);
}

// ================================================================ convert f32 -> f16 (verified r8)
__global__ __launch_bounds__(256) void cvt_f32_f16(const float* __restrict__ s,
                                                   unsigned short* __restrict__ d, int n4) {
  int i = blockIdx.x * 256 + threadIdx.x;
  if (i >= n4) return;
  float4 v = ((const float4*)s)[i];
  ushort4 o;
  o.x = f2h(v.x); o.y = f2h(v.y); o.z = f2h(v.z); o.w = f2h(v.w);
  ((ushort4*)d)[i] = o;
}

// ---- batched weight convert: grid.y selects tensor (all NW elements)
__global__ __launch_bounds__(256) void cvt_weights(
    const float* __restrict__ w0, const float* __restrict__ w1,
    const float* __restrict__ w2, const float* __restrict__ w3,
    unsigned short* __restrict__ d0, unsigned short* __restrict__ d1,
    unsigned short* __restrict__ d2, unsigned short* __restrict__ d3, int n4) {
  int i = blockIdx.x * 256 + threadIdx.x;
  if (i >= n4) return;
  const float* s = (blockIdx.y == 0) ? w0 : (blockIdx.y == 1) ? w1 : (blockIdx.y == 2) ? w2 : w3;
  unsigned short* d = (blockIdx.y == 0) ? d0 : (blockIdx.y == 1) ? d1 : (blockIdx.y == 2) ? d2 : d3;
  float4 v = ((const float4*)s)[i];
  ushort4 o;
  o.x = f2h(v.x); o.y = f2h(v.y); o.z = f2h(v.z); o.w = f2h(v.w);
  ((ushort4*)d)[i] = o;
}

// ================================================================ MFMA f16 GEMM-NT, async staging
// Same LDS layout / fragment / epilogue formulas as the r8-verified kernel; only the
// staging move is global_load_lds width-16 (m97 pattern, wave-uniform dest + lane*16).
__device__ __forceinline__ void storeC(float* p, float v) { *p = v; }
__device__ __forceinline__ void storeC(unsigned short* p, float v) { *p = f2h(v); }

template <typename OutT>
__global__ __launch_bounds__(256) void gemm_nt_f16(const unsigned short* __restrict__ A,
                                                   const unsigned short* __restrict__ B,
                                                   OutT* __restrict__ C) {
  __shared__ alignas(16) unsigned short As[128 * 32];
  __shared__ alignas(16) unsigned short Bs[128 * 32];
  const int tid  = threadIdx.x;
  const int lane = tid & 63, w = tid >> 6;
  const int c = lane & 15, g = lane >> 4;
  const int wr = w >> 1, wc = w & 1;
  const int m0 = blockIdx.y * 128, n0 = blockIdx.x * 128;

  float4_t acc[4][4];
#pragma unroll
  for (int m = 0; m < 4; ++m)
#pragma unroll
    for (int n = 0; n < 4; ++n) acc[m][n] = (float4_t){0.f, 0.f, 0.f, 0.f};

  for (int k0 = 0; k0 < 1024; k0 += 32) {
    __syncthreads();
#pragma unroll
    for (int r = 0; r < 2; ++r) {
      const int idx = r * 256 + tid;          // 16B chunk idx; LDS byte off = idx*16
      const int row = idx >> 2, kc = (idx & 3) * 8;
      async_copy16(A + (size_t)(m0 + row) * 1024 + k0 + kc, As + r * 2048 + w * 512);
      async_copy16(B + (size_t)(n0 + row) * 1024 + k0 + kc, Bs + r * 2048 + w * 512);
    }
    __syncthreads();   // compiler drains vmcnt before barrier
    half8_t af[4], bf[4];
#pragma unroll
    for (int m = 0; m < 4; ++m) af[m] = *(const half8_t*)&As[(wr * 64 + m * 16 + c) * 32 + g * 8];
#pragma unroll
    for (int n = 0; n < 4; ++n) bf[n] = *(const half8_t*)&Bs[(wc * 64 + n * 16 + c) * 32 + g * 8];
#pragma unroll
    for (int m = 0; m < 4; ++m)
#pragma unroll
      for (int n = 0; n < 4; ++n)
        acc[m][n] = __builtin_amdgcn_mfma_f32_16x16x32_f16(af[m], bf[n], acc[m][n], 0, 0, 0);
  }
#pragma unroll
  for (int m = 0; m < 4; ++m)
#pragma unroll
    for (int j = 0; j < 4; ++j) {
      const int row = m0 + wr * 64 + m * 16 + g * 4 + j;
#pragma unroll
      for (int n = 0; n < 4; ++n) {
        const int col = n0 + wc * 64 + n * 16 + c;
        storeC(C + (size_t)row * 1024 + col, acc[m][n][j]);
      }
    }
}

// ================================================================ evolve + LayerNorm (verified math; chunk 32, warm 64)
// 0.7^64 ~ 1.2e-10 => truncated-warmup recurrence exact at f32 precision.
// grid (T/32 = 64, B*H = 32), block 64 -> 2048 waves (8/CU).
__global__ __launch_bounds__(64) void evolve_ln_f32(
    const float* __restrict__ q, const float* __restrict__ k,
    const float* __restrict__ er_p, const float* __restrict__ md_p,
    const float* __restrict__ tw, const float* __restrict__ qgamma,
    const float* __restrict__ qbeta, const float* __restrict__ kgamma,
    const float* __restrict__ kbeta,
    unsigned short* __restrict__ eq, unsigned short* __restrict__ ek) {
  const int lane = threadIdx.x;
  const int t0 = blockIdx.x * 32;
  const int bh = blockIdx.y;
  const int b = bh >> 4, h = bh & 15;
  const float sig_er = 1.f / (1.f + expf(-er_p[0]));
  const float smd    = 1.f / (1.f + expf(-md_p[0]));
  const float wv = tw[lane];
  const float gq = qgamma[lane], bq = qbeta[lane];
  const float gk = kgamma[lane], bk = kbeta[lane];
  const size_t base = ((size_t)b * T_SEQ) * DMODEL + h * HDIM + lane;

  float mem = 0.f;
  const int start = (t0 >= 64) ? (t0 - 64) : 0;
  for (int t = start; t < t0; ++t)
    mem = 0.7f * mem + 0.3f * q[base + (size_t)t * DMODEL];

  for (int t = t0; t < t0 + 32; ++t) {
    const float qv = q[base + (size_t)t * DMODEL];
    const float kv = k[base + (size_t)t * DMODEL];
    const float ts = sinf(sig_er * (float)(t + 1) * wv);
    const float xq = qv + ts + smd * mem;
    const float xk = kv + 0.5f * ts + 0.3f * smd * mem;
    float s1 = xq, s2 = xq * xq, s3 = xk, s4 = xk * xk;
#pragma unroll
    for (int off = 32; off > 0; off >>= 1) {
      s1 += __shfl_xor(s1, off);
      s2 += __shfl_xor(s2, off);
      s3 += __shfl_xor(s3, off);
      s4 += __shfl_xor(s4, off);
    }
    const float mq = s1 * (1.f / 64.f);
    const float vq = fmaxf(s2 * (1.f / 64.f) - mq * mq, 0.f);
    const float mk = s3 * (1.f / 64.f);
    const float vk = fmaxf(s4 * (1.f / 64.f) - mk * mk, 0.f);
    eq[base + (size_t)t * DMODEL] = f2h((xq - mq) * rsqrtf(vq + 1e-5f) * gq + bq);
    ek[base + (size_t)t * DMODEL] = f2h((xk - mk) * rsqrtf(vk + 1e-5f) * gk + bk);
    mem = 0.7f * mem + 0.3f * qv;
  }
}

// ================================================================ MFMA flash attention (verified r16)
__global__ __launch_bounds__(256) void attn_fused(
    const unsigned short* __restrict__ eq, const unsigned short* __restrict__ ek,
    const unsigned short* __restrict__ v, unsigned short* __restrict__ o) {
  __shared__ alignas(16) float Ssh[4][16][36];
  __shared__ float Alds[4][16];
  __shared__ float Llds[4][16];
  const int tid = threadIdx.x;
  const int lane = tid & 63, w = tid >> 6;
  const int c = lane & 15, g = lane >> 4;
  const int p = blockIdx.x * 4 + w;
  const int bh = blockIdx.y;
  const int b = bh >> 4, h = bh & 15;
  const size_t head = ((size_t)b * T_SEQ) * DMODEL + h * HDIM;

  for (int half = 0; half < 2; ++half) {
    const int sub = half ? (127 - p) : p;
    const int qw = sub * 16;
    const int qrow = qw + c;

    const half8_t aq0 = *(const half8_t*)(eq + head + (size_t)qrow * DMODEL + g * 8);
    const half8_t aq1 = *(const half8_t*)(eq + head + (size_t)qrow * DMODEL + 32 + g * 8);

    float4_t acc[4];
#pragma unroll
    for (int n = 0; n < 4; ++n) acc[n] = (float4_t){0.f, 0.f, 0.f, 0.f};
    float mrun = -1e30f, lsum = 0.f;

    const int ntiles = (qw >> 5) + 1;
    for (int tile = 0; tile < ntiles; ++tile) {
      const int s0 = tile * 32;
#pragma unroll
      for (int st = 0; st < 2; ++st) {
        const unsigned short* ekr = ek + head + (size_t)(s0 + st * 16 + c) * DMODEL;
        const half8_t bk0 = *(const half8_t*)(ekr + g * 8);
        const half8_t bk1 = *(const half8_t*)(ekr + 32 + g * 8);
        float4_t z = (float4_t){0.f, 0.f, 0.f, 0.f};
        z = __builtin_amdgcn_mfma_f32_16x16x32_f16(aq0, bk0, z, 0, 0, 0);
        z = __builtin_amdgcn_mfma_f32_16x16x32_f16(aq1, bk1, z, 0, 0, 0);
#pragma unroll
        for (int j = 0; j < 4; ++j)
          Ssh[w][g * 4 + j][st * 16 + c] = z[j] * 0.125f;
      }

      float pf[8];
      float tmax = -1e30f;
#pragma unroll
      for (int e = 0; e < 8; ++e) {
        const int sa = s0 + g * 8 + e;
        const float val = (sa <= qrow) ? Ssh[w][c][g * 8 + e] : -1e30f;
        pf[e] = val;
        tmax = fmaxf(tmax, val);
      }
      tmax = fmaxf(tmax, __shfl_xor(tmax, 16));
      tmax = fmaxf(tmax, __shfl_xor(tmax, 32));
      const float mnew = fmaxf(mrun, tmax);
      const float alpha = __expf(mrun - mnew);
      mrun = mnew;
      float psum = 0.f;
#pragma unroll
      for (int e = 0; e < 8; ++e) {
        pf[e] = __expf(pf[e] - mnew);
        psum += pf[e];
      }
      psum += __shfl_xor(psum, 16);
      psum += __shfl_xor(psum, 32);
      lsum = lsum * alpha + psum;
      if (g == 0) Alds[w][c] = alpha;

      uint4 pu;
      pu.x = packh2(pf[0], pf[1]);
      pu.y = packh2(pf[2], pf[3]);
      pu.z = packh2(pf[4], pf[5]);
      pu.w = packh2(pf[6], pf[7]);
      const half8_t pa = __builtin_bit_cast(half8_t, pu);

      float af[4];
#pragma unroll
      for (int j = 0; j < 4; ++j) af[j] = Alds[w][g * 4 + j];
#pragma unroll
      for (int n = 0; n < 4; ++n) {
        acc[n][0] *= af[0]; acc[n][1] *= af[1];
        acc[n][2] *= af[2]; acc[n][3] *= af[3];
      }
      const unsigned short* vp = v + head + (size_t)(s0 + g * 8) * DMODEL + c;
#pragma unroll
      for (int n = 0; n < 4; ++n) {
        const unsigned short* vq2 = vp + n * 16;
        uint4 bu;
        bu.x = packu2(vq2[0 * DMODEL], vq2[1 * DMODEL]);
        bu.y = packu2(vq2[2 * DMODEL], vq2[3 * DMODEL]);
        bu.z = packu2(vq2[4 * DMODEL], vq2[5 * DMODEL]);
        bu.w = packu2(vq2[6 * DMODEL], vq2[7 * DMODEL]);
        const half8_t bv = __builtin_bit_cast(half8_t, bu);
        acc[n] = __builtin_amdgcn_mfma_f32_16x16x32_f16(pa, bv, acc[n], 0, 0, 0);
      }
    }

    if (g == 0) Llds[w][c] = lsum;
    float lj[4];
#pragma unroll
    for (int j = 0; j < 4; ++j) lj[j] = 1.f / Llds[w][g * 4 + j];
#pragma unroll
    for (int n = 0; n < 4; ++n)
#pragma unroll
      for (int j = 0; j < 4; ++j)
        o[head + (size_t)(qw + g * 4 + j) * DMODEL + n * 16 + c] = f2h(acc[n][j] * lj[j]);
  }
}

// ================================================================ launch
extern "C" void kernel_launch(void* const* d_in, const int* in_sizes, int n_in,
                              void* d_out, int out_size, void* d_ws, size_t ws_size,
                              hipStream_t stream) {
  const float* x  = (const float*)d_in[0];
  const float* Wq = (const float*)d_in[1];
  const float* Wk = (const float*)d_in[2];
  const float* Wv = (const float*)d_in[3];
  const float* Wo = (const float*)d_in[4];
  const float* er = (const float*)d_in[5];
  const float* md = (const float*)d_in[6];
  const float* tw = (const float*)d_in[7];
  const float* qg = (const float*)d_in[8];
  const float* qb = (const float*)d_in[9];
  const float* kg = (const float*)d_in[10];
  const float* kb = (const float*)d_in[11];

  const size_t NX = (size_t)2 * T_SEQ * DMODEL;   // 4194304
  const size_t NW = (size_t)DMODEL * DMODEL;      // 1048576

  // Workspace 64 MB, verified r16 overlay.
  unsigned short* xh  = (unsigned short*)d_ws;            // [0,8)
  unsigned short* woh = xh + NX;                          // [8,10)
  unsigned short* wqh = woh + NW;                         // [10,12)
  unsigned short* wkh = wqh + NW;                         // [12,14)
  unsigned short* wvh = wkh + NW;                         // [14,16)
  float* qf  = (float*)(wvh + NW);                        // [16,32)
  float* kf  = qf + NX;                                   // [32,48)
  unsigned short* ekh = (unsigned short*)(kf + NX);       // [48,56)
  unsigned short* vh  = ekh + NX;                         // [56,64)
  unsigned short* eqh = xh;                               // [0,8) overlay (xh dead post-QKV)
  unsigned short* aoh = (unsigned short*)kf;              // [32,40) overlay (kf dead post-evolve)

  const int n4x = (int)(NX / 4), n4w = (int)(NW / 4);

  cvt_f32_f16<<<n4x / 256, 256, 0, stream>>>(x, xh, n4x);
  cvt_weights<<<dim3(n4w / 256, 4), 256, 0, stream>>>(Wq, Wk, Wv, Wo,
                                                      wqh, wkh, wvh, woh, n4w);

  dim3 ggrid(DMODEL / 128, (2 * T_SEQ) / 128);   // (8, 32)
  gemm_nt_f16<float><<<ggrid, 256, 0, stream>>>(xh, wqh, qf);
  gemm_nt_f16<float><<<ggrid, 256, 0, stream>>>(xh, wkh, kf);
  gemm_nt_f16<unsigned short><<<ggrid, 256, 0, stream>>>(xh, wvh, vh);

  evolve_ln_f32<<<dim3(T_SEQ / 32, 32), 64, 0, stream>>>(qf, kf, er, md, tw,
                                                         qg, qb, kg, kb, eqh, ekh);

  attn_fused<<<dim3(16, 32), 256, 0, stream>>>(eqh, ekh, vh, aoh);

  gemm_nt_f16<float><<<ggrid, 256, 0, stream>>>(aoh, woh, (float*)d_out);
}